// Round 1
// baseline (1016.499 us; speedup 1.0000x reference)
//
#include <hip/hip_runtime.h>

typedef __bf16 bf16x8 __attribute__((ext_vector_type(8)));
typedef float f32x4 __attribute__((ext_vector_type(4)));

#define BETA 0.8f
#define LAM 1e-4f

__device__ __forceinline__ unsigned short f2bf(float x) {
  unsigned u = __float_as_uint(x);
  u += 0x7FFFu + ((u >> 16) & 1u);          // RTNE to bf16
  return (unsigned short)(u >> 16);
}
__device__ __forceinline__ float bf2f(unsigned short h) {
  return __uint_as_float(((unsigned)h) << 16);
}
__device__ __forceinline__ void split2(float x, unsigned short& h, unsigned short& l) {
  h = f2bf(x);
  l = f2bf(x - bf2f(h));
}
__device__ __forceinline__ float fast_tanh(float x) {
  float e = __expf(2.0f * x);
  return 1.0f - 2.0f / (e + 1.0f);          // exact at +-inf, ~1e-7 rel error
}

__device__ __forceinline__ void async_cp16(const void* g, void* l) {
  __builtin_amdgcn_global_load_lds(
      (const __attribute__((address_space(1))) void*)g,
      (__attribute__((address_space(3))) void*)l, 16, 0, 0);
}

// ---------------------------------------------------------------------------
// bf16x3 GEMM: out[M,N] from A[M,K] (hi/lo bf16) * B^T[N,K] (hi/lo bf16).
// MODE 0: out = acc + bias[n]           (Xb = x@Wx + b)
// MODE 1: out = tanh(acc + add[m,n]) - zin[m,n]   (g = f(z) - z)
// 128x128 tile, BK=32, 4 waves 2x2, hi|lo interleaved 128B LDS rows,
// XOR-swizzled (slot ^= row&7) staging via global_load_lds + swizzled ds_read.
// ---------------------------------------------------------------------------
template<int MODE>
__global__ __launch_bounds__(256, 2)
void gemm_bf16x3(const unsigned short* __restrict__ Ahi,
                 const unsigned short* __restrict__ Alo,
                 const unsigned short* __restrict__ Bhi,
                 const unsigned short* __restrict__ Blo,
                 const float* __restrict__ addv,
                 const float* __restrict__ zin,
                 float* __restrict__ outp,
                 int M, int N, int K)
{
  __shared__ unsigned short As[128 * 64];   // [row][ hi k0..31 | lo k0..31 ] swizzled
  __shared__ unsigned short Bs[128 * 64];

  const int tid   = threadIdx.x;
  const int lane  = tid & 63;
  const int w     = tid >> 6;
  const int wrow  = w >> 1, wcol = w & 1;
  const int lane15 = lane & 15;
  const int lhalf  = lane >> 4;

  const int m0 = blockIdx.y * 128;
  const int n0 = blockIdx.x * 128;

  // staging geometry: wave stages 4 chunks (8 rows x 128B) of A and of B.
  const int srow8 = lane >> 3;                 // row within chunk (== row&7)
  const int sslot = (lane & 7) ^ srow8;        // pre-swizzled source slot 0..7
  const int s_hi  = (sslot < 4);
  const int s_ko  = (sslot & 3) * 8;           // k element offset of the 16B slot

  f32x4 acc[4][4];
#pragma unroll
  for (int i = 0; i < 4; ++i)
#pragma unroll
    for (int j = 0; j < 4; ++j) acc[i][j] = f32x4{0.f, 0.f, 0.f, 0.f};

  for (int kt = 0; kt < K; kt += 32) {
#pragma unroll
    for (int t = 0; t < 4; ++t) {
      int c = w * 4 + t;                       // chunk 0..15
      int row = c * 8 + srow8;
      const unsigned short* sa = (s_hi ? Ahi : Alo) + (size_t)(m0 + row) * K + kt + s_ko;
      async_cp16(sa, &As[c * 512]);
      const unsigned short* sb = (s_hi ? Bhi : Blo) + (size_t)(n0 + row) * K + kt + s_ko;
      async_cp16(sb, &Bs[c * 512]);
    }
    __syncthreads();                            // drains vmcnt before barrier

    bf16x8 ah[4], al[4], bh[4], bl[4];
#pragma unroll
    for (int mi = 0; mi < 4; ++mi) {
      int r = wrow * 64 + mi * 16 + lane15;
      const char* base = (const char*)As + r * 128;
      int sw = (r & 7) << 4;
      ah[mi] = *(const bf16x8*)(base + ((lhalf << 4) ^ sw));
      al[mi] = *(const bf16x8*)(base + ((64 + (lhalf << 4)) ^ sw));
    }
#pragma unroll
    for (int ni = 0; ni < 4; ++ni) {
      int r = wcol * 64 + ni * 16 + lane15;
      const char* base = (const char*)Bs + r * 128;
      int sw = (r & 7) << 4;
      bh[ni] = *(const bf16x8*)(base + ((lhalf << 4) ^ sw));
      bl[ni] = *(const bf16x8*)(base + ((64 + (lhalf << 4)) ^ sw));
    }
#pragma unroll
    for (int mi = 0; mi < 4; ++mi)
#pragma unroll
      for (int ni = 0; ni < 4; ++ni) {
        acc[mi][ni] = __builtin_amdgcn_mfma_f32_16x16x32_bf16(ah[mi], bh[ni], acc[mi][ni], 0, 0, 0);
        acc[mi][ni] = __builtin_amdgcn_mfma_f32_16x16x32_bf16(ah[mi], bl[ni], acc[mi][ni], 0, 0, 0);
        acc[mi][ni] = __builtin_amdgcn_mfma_f32_16x16x32_bf16(al[mi], bh[ni], acc[mi][ni], 0, 0, 0);
      }
    __syncthreads();
  }

  // epilogue: C/D layout col=lane&15, row=(lane>>4)*4+reg  [m89-verified]
#pragma unroll
  for (int mi = 0; mi < 4; ++mi)
#pragma unroll
    for (int ni = 0; ni < 4; ++ni)
#pragma unroll
      for (int j = 0; j < 4; ++j) {
        int m = m0 + wrow * 64 + mi * 16 + lhalf * 4 + j;
        int n = n0 + wcol * 64 + ni * 16 + lane15;
        size_t idx = (size_t)m * N + n;
        float v = acc[mi][ni][j];
        if (MODE == 0) {
          outp[idx] = v + addv[n];
        } else {
          v = fast_tanh(v + addv[idx]);
          outp[idx] = v - zin[idx];
        }
      }
}

// --- elementwise / small kernels -------------------------------------------

__global__ void split_rows_k(const float* __restrict__ X, unsigned short* __restrict__ H,
                             unsigned short* __restrict__ L, long n4)
{
  long i = (long)blockIdx.x * blockDim.x + threadIdx.x;
  long stride = (long)gridDim.x * blockDim.x;
  for (; i < n4; i += stride) {
    float4 v = ((const float4*)X)[i];
    ushort4 h, l;
    split2(v.x, h.x, l.x); split2(v.y, h.y, l.y);
    split2(v.z, h.z, l.z); split2(v.w, h.w, l.w);
    ((ushort4*)H)[i] = h; ((ushort4*)L)[i] = l;
  }
}

// W[k][n] -> Th/Tl[n][k]  (split + transpose)
__global__ void split_transpose_k(const float* __restrict__ W,
                                  unsigned short* __restrict__ Th,
                                  unsigned short* __restrict__ Tl, int D)
{
  __shared__ float tile[32][33];
  int n0 = blockIdx.x * 32, k0 = blockIdx.y * 32;
  int tx = threadIdx.x, ty = threadIdx.y;
  for (int r = ty; r < 32; r += 8)
    tile[r][tx] = W[(size_t)(k0 + r) * D + n0 + tx];
  __syncthreads();
  for (int r = ty; r < 32; r += 8) {
    float v = tile[tx][r];                       // W[k0+tx][n0+r]
    unsigned short h, l; split2(v, h, l);
    size_t o = (size_t)(n0 + r) * D + k0 + tx;
    Th[o] = h; Tl[o] = l;
  }
}

// i=0: g0 = tanh(Xb); z1 = beta*g0; also bf16-split z1
__global__ void iter0_k(const float* __restrict__ Xb, float* __restrict__ g0,
                        float* __restrict__ z1, unsigned short* __restrict__ zh,
                        unsigned short* __restrict__ zl, long n4)
{
  long i = (long)blockIdx.x * blockDim.x + threadIdx.x;
  long stride = (long)gridDim.x * blockDim.x;
  for (; i < n4; i += stride) {
    float4 xb = ((const float4*)Xb)[i];
    float4 f, z;
    f.x = fast_tanh(xb.x); f.y = fast_tanh(xb.y);
    f.z = fast_tanh(xb.z); f.w = fast_tanh(xb.w);
    z.x = BETA * f.x; z.y = BETA * f.y; z.z = BETA * f.z; z.w = BETA * f.w;
    ((float4*)g0)[i] = f;
    ((float4*)z1)[i] = z;
    ushort4 h, l;
    split2(z.x, h.x, l.x); split2(z.y, h.y, l.y);
    split2(z.z, h.z, l.z); split2(z.w, h.w, l.w);
    ((ushort4*)zh)[i] = h; ((ushort4*)zl)[i] = l;
  }
}

__global__ void simple_update_k(const float* __restrict__ z, const float* __restrict__ g,
                                float* __restrict__ zn, unsigned short* __restrict__ zh,
                                unsigned short* __restrict__ zl, long n4)
{
  long i = (long)blockIdx.x * blockDim.x + threadIdx.x;
  long stride = (long)gridDim.x * blockDim.x;
  for (; i < n4; i += stride) {
    float4 zv = ((const float4*)z)[i];
    float4 gv = ((const float4*)g)[i];
    float4 o;
    o.x = zv.x + BETA * gv.x; o.y = zv.y + BETA * gv.y;
    o.z = zv.z + BETA * gv.z; o.w = zv.w + BETA * gv.w;
    ((float4*)zn)[i] = o;
    ushort4 h, l;
    split2(o.x, h.x, l.x); split2(o.y, h.y, l.y);
    split2(o.z, h.z, l.z); split2(o.w, h.w, l.w);
    ((ushort4*)zh)[i] = h; ((ushort4*)zl)[i] = l;
  }
}

// per-row 2x2 gram solve -> gamma[row][2]
__global__ __launch_bounds__(256) void gram_k(const float* __restrict__ g,
                                              const float* __restrict__ gm1,
                                              const float* __restrict__ gm2,
                                              float* __restrict__ gamma, int D)
{
  int row = blockIdx.x;
  const float4* G0 = (const float4*)(g   + (size_t)row * D);
  const float4* G1 = (const float4*)(gm1 + (size_t)row * D);
  const float4* G2 = (const float4*)(gm2 + (size_t)row * D);
  float s00 = 0, s01 = 0, s11 = 0, r0 = 0, r1 = 0;
  int n4 = D >> 2;
  for (int t = threadIdx.x; t < n4; t += 256) {
    float4 a = G0[t], b = G1[t], c = G2[t];
    {
      float gg = a.x, d0 = gg - b.x, d1 = gg - c.x;
      s00 += d0 * d0; s01 += d0 * d1; s11 += d1 * d1; r0 += d0 * gg; r1 += d1 * gg;
    }
    {
      float gg = a.y, d0 = gg - b.y, d1 = gg - c.y;
      s00 += d0 * d0; s01 += d0 * d1; s11 += d1 * d1; r0 += d0 * gg; r1 += d1 * gg;
    }
    {
      float gg = a.z, d0 = gg - b.z, d1 = gg - c.z;
      s00 += d0 * d0; s01 += d0 * d1; s11 += d1 * d1; r0 += d0 * gg; r1 += d1 * gg;
    }
    {
      float gg = a.w, d0 = gg - b.w, d1 = gg - c.w;
      s00 += d0 * d0; s01 += d0 * d1; s11 += d1 * d1; r0 += d0 * gg; r1 += d1 * gg;
    }
  }
  for (int off = 32; off > 0; off >>= 1) {
    s00 += __shfl_down(s00, off); s01 += __shfl_down(s01, off);
    s11 += __shfl_down(s11, off); r0 += __shfl_down(r0, off); r1 += __shfl_down(r1, off);
  }
  __shared__ float red[4][5];
  int lane = threadIdx.x & 63, wv = threadIdx.x >> 6;
  if (lane == 0) { red[wv][0] = s00; red[wv][1] = s01; red[wv][2] = s11; red[wv][3] = r0; red[wv][4] = r1; }
  __syncthreads();
  if (threadIdx.x == 0) {
    s00 = red[0][0] + red[1][0] + red[2][0] + red[3][0];
    s01 = red[0][1] + red[1][1] + red[2][1] + red[3][1];
    s11 = red[0][2] + red[1][2] + red[2][2] + red[3][2];
    r0  = red[0][3] + red[1][3] + red[2][3] + red[3][3];
    r1  = red[0][4] + red[1][4] + red[2][4] + red[3][4];
    float a_ = s00 + LAM, d_ = s11 + LAM, b_ = s01;
    float det = a_ * d_ - b_ * b_ + 1e-8f;
    gamma[row * 2]     = (d_ * r0 - b_ * r1) / det;
    gamma[row * 2 + 1] = (a_ * r1 - b_ * r0) / det;
  }
}

__global__ void anderson_update_k(const float* __restrict__ z, const float* __restrict__ zm1,
                                  const float* __restrict__ zm2, const float* __restrict__ g,
                                  const float* __restrict__ gm1, const float* __restrict__ gm2,
                                  const float* __restrict__ gamma,
                                  float* __restrict__ zn, unsigned short* __restrict__ zh,
                                  unsigned short* __restrict__ zl, long n4, int logD4, int write_bf)
{
  long i = (long)blockIdx.x * blockDim.x + threadIdx.x;
  long stride = (long)gridDim.x * blockDim.x;
  for (; i < n4; i += stride) {
    long row = i >> logD4;
    float c0 = gamma[row * 2], c1 = gamma[row * 2 + 1];
    float4 zv = ((const float4*)z)[i],  z1 = ((const float4*)zm1)[i], z2 = ((const float4*)zm2)[i];
    float4 gv = ((const float4*)g)[i],  g1 = ((const float4*)gm1)[i], g2 = ((const float4*)gm2)[i];
    float4 o;
    o.x = zv.x + BETA * gv.x - (c0 * ((zv.x - z1.x) + BETA * (gv.x - g1.x)) + c1 * ((zv.x - z2.x) + BETA * (gv.x - g2.x)));
    o.y = zv.y + BETA * gv.y - (c0 * ((zv.y - z1.y) + BETA * (gv.y - g1.y)) + c1 * ((zv.y - z2.y) + BETA * (gv.y - g2.y)));
    o.z = zv.z + BETA * gv.z - (c0 * ((zv.z - z1.z) + BETA * (gv.z - g1.z)) + c1 * ((zv.z - z2.z) + BETA * (gv.z - g2.z)));
    o.w = zv.w + BETA * gv.w - (c0 * ((zv.w - z1.w) + BETA * (gv.w - g1.w)) + c1 * ((zv.w - z2.w) + BETA * (gv.w - g2.w)));
    ((float4*)zn)[i] = o;
    if (write_bf) {
      ushort4 h, l;
      split2(o.x, h.x, l.x); split2(o.y, h.y, l.y);
      split2(o.z, h.z, l.z); split2(o.w, h.w, l.w);
      ((ushort4*)zh)[i] = h; ((ushort4*)zl)[i] = l;
    }
  }
}

// ---------------------------------------------------------------------------

extern "C" void kernel_launch(void* const* d_in, const int* in_sizes, int n_in,
                              void* d_out, int out_size, void* d_ws, size_t ws_size,
                              hipStream_t stream)
{
  const float* x  = (const float*)d_in[0];
  const float* Wz = (const float*)d_in[1];
  const float* Wx = (const float*)d_in[2];
  const float* b  = (const float*)d_in[3];
  const int D = in_sizes[3];
  const int B = in_sizes[0] / D;
  const size_t BD = (size_t)B * D, DD = (size_t)D * D;

  float* Xb  = (float*)d_ws;
  float* gb0 = Xb + BD;
  float* gb1 = gb0 + BD;
  float* gb2 = gb1 + BD;
  float* zs1 = gb2 + BD;
  float* zs2 = zs1 + BD;
  unsigned short* zhi = (unsigned short*)(zs2 + BD);
  unsigned short* zlo = zhi + BD;
  unsigned short* Wth = zlo + BD;
  unsigned short* Wtl = Wth + DD;
  float* gamma = (float*)(Wtl + DD);

  float* zslot[3] = { (float*)d_out, zs1, zs2 };
  float* gslot[3] = { gb0, gb1, gb2 };

  dim3 tblk(32, 8);
  dim3 tgrd(D / 32, D / 32);
  dim3 ggrd(D / 128, B / 128);
  long n4 = (long)(BD >> 2);
  int logD4 = 31 - __builtin_clz((unsigned)(D >> 2));
  const int ebl = 2048;

  // Xb = x @ Wx + b (loop-invariant)
  split_transpose_k<<<tgrd, tblk, 0, stream>>>(Wx, Wth, Wtl, D);
  split_rows_k<<<ebl, 256, 0, stream>>>(x, zhi, zlo, n4);
  gemm_bf16x3<0><<<ggrd, 256, 0, stream>>>(zhi, zlo, Wth, Wtl, b, nullptr, Xb, B, D, D);
  split_transpose_k<<<tgrd, tblk, 0, stream>>>(Wz, Wth, Wtl, D);

  // i = 0 (z=0): g0 = tanh(Xb), z1 = beta*g0
  iter0_k<<<ebl, 256, 0, stream>>>(Xb, gslot[0], zslot[1], zhi, zlo, n4);

  for (int i = 1; i <= 5; ++i) {
    float* zi = zslot[i % 3];
    float* gi = gslot[i % 3];
    gemm_bf16x3<1><<<ggrd, 256, 0, stream>>>(zhi, zlo, Wth, Wtl, Xb, zi, gi, B, D, D);
    float* zn = zslot[(i + 1) % 3];
    if (i < 3) {
      simple_update_k<<<ebl, 256, 0, stream>>>(zi, gi, zn, zhi, zlo, n4);
    } else {
      gram_k<<<B, 256, 0, stream>>>(gi, gslot[(i - 1) % 3], gslot[(i - 2) % 3], gamma, D);
      anderson_update_k<<<ebl, 256, 0, stream>>>(zi, zslot[(i - 1) % 3], zslot[(i - 2) % 3],
          gi, gslot[(i - 1) % 3], gslot[(i - 2) % 3], gamma, zn, zhi, zlo, n4, logD4, i < 5 ? 1 : 0);
    }
  }
}

// Round 4
// 966.142 us; speedup vs baseline: 1.0521x; 1.0521x over previous
//
#include <hip/hip_runtime.h>

typedef __bf16 bf16x8 __attribute__((ext_vector_type(8)));
typedef float f32x4 __attribute__((ext_vector_type(4)));

#define BETA 0.8f
#define LAM 1e-4f

__device__ __forceinline__ unsigned short f2bf(float x) {
  unsigned u = __float_as_uint(x);
  u += 0x7FFFu + ((u >> 16) & 1u);          // RTNE to bf16
  return (unsigned short)(u >> 16);
}
__device__ __forceinline__ float bf2f(unsigned short h) {
  return __uint_as_float(((unsigned)h) << 16);
}
__device__ __forceinline__ void split2(float x, unsigned short& h, unsigned short& l) {
  h = f2bf(x);
  l = f2bf(x - bf2f(h));
}
__device__ __forceinline__ float fast_tanh(float x) {
  float e = __expf(2.0f * x);
  return 1.0f - 2.0f / (e + 1.0f);
}

__device__ __forceinline__ void async_cp16(const void* g, void* l) {
  __builtin_amdgcn_global_load_lds(
      (const __attribute__((address_space(1))) void*)g,
      (__attribute__((address_space(3))) void*)l, 16, 0, 0);
}

// ---------------------------------------------------------------------------
// bf16x3 GEMM, BK=64, 128x128 tile, 4 waves 2x2, single 64KiB LDS buffer.
// Row layout: 256B = [hi k0..63 | lo k0..63], 16B slots, XOR-swizzle
// slot' = slot ^ (row&7) applied identically on stage-source and ds_read
// (both-sides rule: global_load_lds dest is linear, source is pre-swizzled).
// MODE 0: gout = acc + bias[n]                      (Xb = x@Wx + b)
// MODE 1: v=tanh(acc+Xb); g=v-zin; u=zin+beta*g; writes g,u
// zin/uout may alias (pointwise same-index, own-tile only) -> NOT __restrict__.
// NOTE: do NOT write bf16 u-splits here — zhi/zlo are this kernel's A input,
// read across the whole block-row by other blocks (cross-block race).
// ---------------------------------------------------------------------------
template<int MODE>
__global__ __launch_bounds__(256, 2)
void gemm_bf16x3(const unsigned short* __restrict__ Ahi,
                 const unsigned short* __restrict__ Alo,
                 const unsigned short* __restrict__ Bhi,
                 const unsigned short* __restrict__ Blo,
                 const float* __restrict__ addv,   // MODE0: bias[n]; MODE1: Xb[m,n]
                 const float* zin,
                 float* __restrict__ gout,
                 float* uout,
                 int M, int N, int K)
{
  __shared__ unsigned short As[128 * 128];   // 32 KiB
  __shared__ unsigned short Bs[128 * 128];   // 32 KiB

  const int tid    = threadIdx.x;
  const int lane   = tid & 63;
  const int w      = tid >> 6;
  const int wrow   = w >> 1, wcol = w & 1;
  const int lane15 = lane & 15;
  const int q      = lane >> 4;              // k-quarter 0..3 / C-row group

  // XCD-aware swizzle (grid.x = (M/128)*(N/128), multiple of 8):
  const int nwg = gridDim.x;
  const int bid = blockIdx.x;
  const int sw  = (bid & 7) * (nwg >> 3) + (bid >> 3);
  const int nby = M >> 7;
  const int by  = sw % nby;                  // column-major: each XCD gets
  const int bx  = sw / nby;                  // ~2 B-column panels (L2-fit)
  const int m0 = by * 128;
  const int n0 = bx * 128;

  // staging geometry: chunk = 4 rows x 256B = 1024B; 32 chunks per matrix.
  const int rin   = lane >> 4;               // row within chunk
  const int pslot = lane & 15;               // physical 16B slot in row

  f32x4 acc[4][4];
#pragma unroll
  for (int i = 0; i < 4; ++i)
#pragma unroll
    for (int j = 0; j < 4; ++j) acc[i][j] = f32x4{0.f, 0.f, 0.f, 0.f};

  for (int kt = 0; kt < K; kt += 64) {
#pragma unroll
    for (int t = 0; t < 8; ++t) {
      int c   = t * 4 + w;                   // chunk 0..31
      int row = c * 4 + rin;                 // 0..127
      int ls  = pslot ^ (row & 7);           // logical slot (bit3 = hi/lo kept)
      const unsigned short* sa = (ls < 8 ? Ahi : Alo)
          + (size_t)(m0 + row) * K + kt + (ls & 7) * 8;
      async_cp16(sa, &As[c * 512]);
      const unsigned short* sb = (ls < 8 ? Bhi : Blo)
          + (size_t)(n0 + row) * K + kt + (ls & 7) * 8;
      async_cp16(sb, &Bs[c * 512]);
    }
    __syncthreads();                         // drains vmcnt + lgkm before use

#pragma unroll
    for (int s = 0; s < 2; ++s) {            // two 16x16x32 k-slices per BK=64
      bf16x8 ah[4], al[4], bh[4], bl[4];
#pragma unroll
      for (int mi = 0; mi < 4; ++mi) {
        int r = wrow * 64 + mi * 16 + lane15;
        const char* rowp = (const char*)As + r * 256;
        int x7 = r & 7;
        int sl = (s * 4 + q) ^ x7;
        ah[mi] = *(const bf16x8*)(rowp + sl * 16);
        al[mi] = *(const bf16x8*)(rowp + (8 + sl) * 16);
      }
#pragma unroll
      for (int ni = 0; ni < 4; ++ni) {
        int r = wcol * 64 + ni * 16 + lane15;
        const char* rowp = (const char*)Bs + r * 256;
        int x7 = r & 7;
        int sl = (s * 4 + q) ^ x7;
        bh[ni] = *(const bf16x8*)(rowp + sl * 16);
        bl[ni] = *(const bf16x8*)(rowp + (8 + sl) * 16);
      }
#pragma unroll
      for (int mi = 0; mi < 4; ++mi)
#pragma unroll
        for (int ni = 0; ni < 4; ++ni) {
          acc[mi][ni] = __builtin_amdgcn_mfma_f32_16x16x32_bf16(ah[mi], bh[ni], acc[mi][ni], 0, 0, 0);
          acc[mi][ni] = __builtin_amdgcn_mfma_f32_16x16x32_bf16(ah[mi], bl[ni], acc[mi][ni], 0, 0, 0);
          acc[mi][ni] = __builtin_amdgcn_mfma_f32_16x16x32_bf16(al[mi], bh[ni], acc[mi][ni], 0, 0, 0);
        }
    }
    __syncthreads();
  }

  // epilogue: C/D layout col=lane&15, row=(lane>>4)*4+reg  [m89-verified]
#pragma unroll
  for (int mi = 0; mi < 4; ++mi)
#pragma unroll
    for (int ni = 0; ni < 4; ++ni)
#pragma unroll
      for (int j = 0; j < 4; ++j) {
        int m = m0 + wrow * 64 + mi * 16 + q * 4 + j;
        int n = n0 + wcol * 64 + ni * 16 + lane15;
        size_t idx = (size_t)m * N + n;
        float a = acc[mi][ni][j];
        if (MODE == 0) {
          gout[idx] = a + addv[n];
        } else {
          float zv = zin[idx];
          float v  = fast_tanh(a + addv[idx]);
          float gg = v - zv;
          gout[idx] = gg;
          uout[idx] = fmaf(BETA, gg, zv);
        }
      }
}

// --- elementwise / small kernels -------------------------------------------

__global__ void split_rows_k(const float* __restrict__ X, unsigned short* __restrict__ H,
                             unsigned short* __restrict__ L, long n4)
{
  long i = (long)blockIdx.x * blockDim.x + threadIdx.x;
  long stride = (long)gridDim.x * blockDim.x;
  for (; i < n4; i += stride) {
    float4 v = ((const float4*)X)[i];
    ushort4 h, l;
    split2(v.x, h.x, l.x); split2(v.y, h.y, l.y);
    split2(v.z, h.z, l.z); split2(v.w, h.w, l.w);
    ((ushort4*)H)[i] = h; ((ushort4*)L)[i] = l;
  }
}

// W[k][n] -> Th/Tl[n][k]  (split + transpose)
__global__ void split_transpose_k(const float* __restrict__ W,
                                  unsigned short* __restrict__ Th,
                                  unsigned short* __restrict__ Tl, int D)
{
  __shared__ float tile[32][33];
  int n0 = blockIdx.x * 32, k0 = blockIdx.y * 32;
  int tx = threadIdx.x, ty = threadIdx.y;
  for (int r = ty; r < 32; r += 8)
    tile[r][tx] = W[(size_t)(k0 + r) * D + n0 + tx];
  __syncthreads();
  for (int r = ty; r < 32; r += 8) {
    float v = tile[tx][r];
    unsigned short h, l; split2(v, h, l);
    size_t o = (size_t)(n0 + r) * D + k0 + tx;
    Th[o] = h; Tl[o] = l;
  }
}

// i=0: u0 = beta*tanh(Xb)  (z=0 -> g0=tanh(Xb) never needed again); split u0
__global__ void iter0_k(const float* __restrict__ Xb, float* __restrict__ u0,
                        unsigned short* __restrict__ zh,
                        unsigned short* __restrict__ zl, long n4)
{
  long i = (long)blockIdx.x * blockDim.x + threadIdx.x;
  long stride = (long)gridDim.x * blockDim.x;
  for (; i < n4; i += stride) {
    float4 xb = ((const float4*)Xb)[i];
    float4 z;
    z.x = BETA * fast_tanh(xb.x); z.y = BETA * fast_tanh(xb.y);
    z.z = BETA * fast_tanh(xb.z); z.w = BETA * fast_tanh(xb.w);
    ((float4*)u0)[i] = z;
    ushort4 h, l;
    split2(z.x, h.x, l.x); split2(z.y, h.y, l.y);
    split2(z.z, h.z, l.z); split2(z.w, h.w, l.w);
    ((ushort4*)zh)[i] = h; ((ushort4*)zl)[i] = l;
  }
}

// per-row 2x2 gram solve -> gamma[row][2]
__global__ __launch_bounds__(256) void gram_k(const float* __restrict__ g,
                                              const float* __restrict__ gm1,
                                              const float* __restrict__ gm2,
                                              float* __restrict__ gamma, int D)
{
  int row = blockIdx.x;
  const float4* G0 = (const float4*)(g   + (size_t)row * D);
  const float4* G1 = (const float4*)(gm1 + (size_t)row * D);
  const float4* G2 = (const float4*)(gm2 + (size_t)row * D);
  float s00 = 0, s01 = 0, s11 = 0, r0 = 0, r1 = 0;
  int n4 = D >> 2;
  for (int t = threadIdx.x; t < n4; t += 256) {
    float4 a = G0[t], b = G1[t], c = G2[t];
    { float gg = a.x, d0 = gg - b.x, d1 = gg - c.x;
      s00 += d0*d0; s01 += d0*d1; s11 += d1*d1; r0 += d0*gg; r1 += d1*gg; }
    { float gg = a.y, d0 = gg - b.y, d1 = gg - c.y;
      s00 += d0*d0; s01 += d0*d1; s11 += d1*d1; r0 += d0*gg; r1 += d1*gg; }
    { float gg = a.z, d0 = gg - b.z, d1 = gg - c.z;
      s00 += d0*d0; s01 += d0*d1; s11 += d1*d1; r0 += d0*gg; r1 += d1*gg; }
    { float gg = a.w, d0 = gg - b.w, d1 = gg - c.w;
      s00 += d0*d0; s01 += d0*d1; s11 += d1*d1; r0 += d0*gg; r1 += d1*gg; }
  }
  for (int off = 32; off > 0; off >>= 1) {
    s00 += __shfl_down(s00, off); s01 += __shfl_down(s01, off);
    s11 += __shfl_down(s11, off); r0 += __shfl_down(r0, off); r1 += __shfl_down(r1, off);
  }
  __shared__ float red[4][5];
  int lane = threadIdx.x & 63, wv = threadIdx.x >> 6;
  if (lane == 0) { red[wv][0]=s00; red[wv][1]=s01; red[wv][2]=s11; red[wv][3]=r0; red[wv][4]=r1; }
  __syncthreads();
  if (threadIdx.x == 0) {
    s00 = red[0][0]+red[1][0]+red[2][0]+red[3][0];
    s01 = red[0][1]+red[1][1]+red[2][1]+red[3][1];
    s11 = red[0][2]+red[1][2]+red[2][2]+red[3][2];
    r0  = red[0][3]+red[1][3]+red[2][3]+red[3][3];
    r1  = red[0][4]+red[1][4]+red[2][4]+red[3][4];
    float a_ = s00 + LAM, d_ = s11 + LAM, b_ = s01;
    float det = a_ * d_ - b_ * b_ + 1e-8f;
    gamma[row * 2]     = (d_ * r0 - b_ * r1) / det;
    gamma[row * 2 + 1] = (a_ * r1 - b_ * r0) / det;
  }
}

// z_new = uc - (c0*(uc-um1) + c1*(uc-um2)); zn may alias uc/um2 (pointwise).
// Writing zh/zl here is safe: no concurrent reader (stream-ordered consumers).
template<int WSPLIT>
__global__ void anderson_update_k(const float* uc, const float* um1,
                                  const float* um2, const float* __restrict__ gamma,
                                  float* zn, unsigned short* __restrict__ zh,
                                  unsigned short* __restrict__ zl, long n4, int logD4)
{
  long i = (long)blockIdx.x * blockDim.x + threadIdx.x;
  long stride = (long)gridDim.x * blockDim.x;
  for (; i < n4; i += stride) {
    long row = i >> logD4;
    float c0 = gamma[row * 2], c1 = gamma[row * 2 + 1];
    float4 u0 = ((const float4*)uc)[i];
    float4 u1 = ((const float4*)um1)[i];
    float4 u2 = ((const float4*)um2)[i];
    float4 o;
    o.x = u0.x - (c0 * (u0.x - u1.x) + c1 * (u0.x - u2.x));
    o.y = u0.y - (c0 * (u0.y - u1.y) + c1 * (u0.y - u2.y));
    o.z = u0.z - (c0 * (u0.z - u1.z) + c1 * (u0.z - u2.z));
    o.w = u0.w - (c0 * (u0.w - u1.w) + c1 * (u0.w - u2.w));
    ((float4*)zn)[i] = o;
    if (WSPLIT) {
      ushort4 h, l;
      split2(o.x, h.x, l.x); split2(o.y, h.y, l.y);
      split2(o.z, h.z, l.z); split2(o.w, h.w, l.w);
      ((ushort4*)zh)[i] = h; ((ushort4*)zl)[i] = l;
    }
  }
}

// ---------------------------------------------------------------------------

extern "C" void kernel_launch(void* const* d_in, const int* in_sizes, int n_in,
                              void* d_out, int out_size, void* d_ws, size_t ws_size,
                              hipStream_t stream)
{
  const float* x  = (const float*)d_in[0];
  const float* Wz = (const float*)d_in[1];
  const float* Wx = (const float*)d_in[2];
  const float* b  = (const float*)d_in[3];
  const int D = in_sizes[3];
  const int B = in_sizes[0] / D;
  const size_t BD = (size_t)B * D, DD = (size_t)D * D;

  float* Xb  = (float*)d_ws;
  float* gb0 = Xb + BD;
  float* gb1 = gb0 + BD;
  float* gb2 = gb1 + BD;
  float* S0  = gb2 + BD;
  float* S1  = S0 + BD;
  unsigned short* zhi = (unsigned short*)(S1 + BD);
  unsigned short* zlo = zhi + BD;
  unsigned short* Wth = zlo + BD;
  unsigned short* Wtl = Wth + DD;
  float* gamma = (float*)(Wtl + DD);

  // u-history slots: u_i -> S[i%3]; S2 = d_out.  z_i locations:
  //   z1=u0(S0) z2=u1(S1) z3=u2(S2) z4->S1 (upd i=3) z5->S2 (upd i=4) z6->d_out
  float* S[3] = { S0, S1, (float*)d_out };
  float* gslot[3] = { gb0, gb1, gb2 };
  const int zin_i[6] = { 0, 0, 1, 2, 1, 2 };

  dim3 tblk(32, 8);
  dim3 tgrd(D / 32, D / 32);
  int ggrd = (D / 128) * (B / 128);
  long n4 = (long)(BD >> 2);
  int logD4 = 31 - __builtin_clz((unsigned)(D >> 2));
  const int ebl = 2048;

  // Xb = x @ Wx + b (loop-invariant)
  split_transpose_k<<<tgrd, tblk, 0, stream>>>(Wx, Wth, Wtl, D);
  split_rows_k<<<ebl, 256, 0, stream>>>(x, zhi, zlo, n4);
  gemm_bf16x3<0><<<ggrd, 256, 0, stream>>>(zhi, zlo, Wth, Wtl, b, nullptr,
                                           Xb, nullptr, B, D, D);
  split_transpose_k<<<tgrd, tblk, 0, stream>>>(Wz, Wth, Wtl, D);

  // i=0: u0 = beta*tanh(Xb) = z1, split
  iter0_k<<<ebl, 256, 0, stream>>>(Xb, S[0], zhi, zlo, n4);

  for (int i = 1; i <= 5; ++i) {
    float* zi = S[zin_i[i]];
    float* gi = gslot[i % 3];
    float* ui = S[i % 3];
    gemm_bf16x3<1><<<ggrd, 256, 0, stream>>>(zhi, zlo, Wth, Wtl, Xb, zi,
                                             gi, ui, B, D, D);
    if (i <= 2) {
      // z_{i+1} = u_i: split in a separate stream-ordered kernel (no race
      // with the GEMM that reads zhi/zlo).
      split_rows_k<<<ebl, 256, 0, stream>>>(ui, zhi, zlo, n4);
    } else {
      gram_k<<<B, 256, 0, stream>>>(gi, gslot[(i - 1) % 3], gslot[(i - 2) % 3], gamma, D);
      float* zn = (i == 5) ? (float*)d_out : S[(i + 1) % 3];
      if (i < 5)
        anderson_update_k<1><<<ebl, 256, 0, stream>>>(S[i % 3], S[(i - 1) % 3], S[(i - 2) % 3],
                                                      gamma, zn, zhi, zlo, n4, logD4);
      else
        anderson_update_k<0><<<ebl, 256, 0, stream>>>(S[i % 3], S[(i - 1) % 3], S[(i - 2) % 3],
                                                      gamma, zn, nullptr, nullptr, n4, logD4);
    }
  }
}